// Round 15
// baseline (349.589 us; speedup 1.0000x reference)
//
#include <hip/hip_runtime.h>
#include <hip/hip_bf16.h>
#include <cstdint>
#include <cmath>

#define S_LEN 4096
#define DMODEL 2048
#define NH 16
#define NKV 4
#define HD 128
#define NQKV 3072  // 2048 Q + 512 K + 512 V

typedef unsigned short u16;
typedef unsigned int u32;
typedef __attribute__((ext_vector_type(8))) __bf16 bf16x8;
typedef __attribute__((ext_vector_type(4))) float f32x4;
typedef __attribute__((ext_vector_type(4))) int i32x4;

__device__ __forceinline__ u16 f2bf(float f) {
  __bf16 h = (__bf16)f;  // RNE
  return __builtin_bit_cast(u16, h);
}
__device__ __forceinline__ float bf2f(u16 u) {
  return (float)__builtin_bit_cast(__bf16, u);
}
__device__ __forceinline__ u32 pk2(float a, float b) {
  return (u32)f2bf(a) | ((u32)f2bf(b) << 16);
}

__device__ __forceinline__ void gload16(const void* g, void* l) {
  __builtin_amdgcn_global_load_lds(
      (const __attribute__((address_space(1))) void*)g,
      (__attribute__((address_space(3))) void*)l, 16, 0, 0);
}

// ---------------- pack / convert ----------------
__global__ void k_f32_to_bf16(const float* __restrict__ src, u16* __restrict__ dst, int n4) {
  int i = blockIdx.x * blockDim.x + threadIdx.x;
  if (i < n4) {
    float4 v = reinterpret_cast<const float4*>(src)[i];
    ushort4 o = make_ushort4(f2bf(v.x), f2bf(v.y), f2bf(v.z), f2bf(v.w));
    reinterpret_cast<ushort4*>(dst)[i] = o;
  }
}

// dst[n][k] = bf16(src[k][n])
__global__ void k_transpose_f32_bf16(const float* __restrict__ src, int srcStride,
                                     u16* __restrict__ dst, int dstStride) {
  __shared__ float tile[32][33];
  int n0 = blockIdx.x * 32, k0 = blockIdx.y * 32;
  int tx = threadIdx.x, ty = threadIdx.y;  // 32 x 8
#pragma unroll
  for (int r = 0; r < 32; r += 8)
    tile[ty + r][tx] = src[(size_t)(k0 + ty + r) * srcStride + n0 + tx];
  __syncthreads();
#pragma unroll
  for (int r = 0; r < 32; r += 8)
    dst[(size_t)(n0 + ty + r) * dstStride + k0 + tx] = f2bf(tile[tx][ty + r]);
}

__global__ void k_transpose_bf16(const u16* __restrict__ src, int srcStride,
                                 u16* __restrict__ dst, int dstStride) {
  __shared__ u16 tile[32][33];
  int n0 = blockIdx.x * 32, k0 = blockIdx.y * 32;
  int tx = threadIdx.x, ty = threadIdx.y;  // 32 x 8
#pragma unroll
  for (int r = 0; r < 32; r += 8)
    tile[ty + r][tx] = src[(size_t)(k0 + ty + r) * srcStride + n0 + tx];
  __syncthreads();
#pragma unroll
  for (int r = 0; r < 32; r += 8)
    dst[(size_t)(n0 + ty + r) * dstStride + k0 + tx] = tile[tx][ty + r];
}

// ---------------- RoPE ----------------
__global__ void k_rope_tab(const int* __restrict__ pos_ids, float2* __restrict__ tab) {
  int idx = blockIdx.x * blockDim.x + threadIdx.x;  // 4096*64
  int s = idx >> 6, dh = idx & 63;
  const float L2B = 13.287712379549449f;  // log2(10000)
  float pos = (float)pos_ids[s];
  float invf = exp2f(-(float)dh * (L2B / 64.0f));
  float ang = pos * invf;
  tab[idx] = make_float2(cosf(ang), sinf(ang));
}

// Q gets 1/sqrt(HD) * LOG2E folded in (softmax runs in exp2 domain).
__global__ void k_rope(const u16* __restrict__ qkv, const float2* __restrict__ tab,
                       u16* __restrict__ Qb, u16* __restrict__ Kb) {
  int s = blockIdx.x;
  const u16* row = qkv + (size_t)s * NQKV;
  const float QSCALE = 0.08838834764831845f * 1.4426950408889634f;
  const int NV = (DMODEL + NKV * HD) / 8;  // 320 vec-chunks of 8
  for (int v8 = threadIdx.x; v8 < NV; v8 += blockDim.x) {
    int c = v8 * 8;
    int d = c & 127;
    int dh0 = d & 63;
    bool lowh = (d < 64);
    ushort4 a0 = *reinterpret_cast<const ushort4*>(row + c);
    ushort4 a1 = *reinterpret_cast<const ushort4*>(row + c + 4);
    ushort4 b0 = *reinterpret_cast<const ushort4*>(row + (c ^ 64));
    ushort4 b1 = *reinterpret_cast<const ushort4*>(row + (c ^ 64) + 4);
    u16 xs[8] = {a0.x, a0.y, a0.z, a0.w, a1.x, a1.y, a1.z, a1.w};
    u16 xp[8] = {b0.x, b0.y, b0.z, b0.w, b1.x, b1.y, b1.z, b1.w};
    u16 ov[8];
    bool isQ = (c < DMODEL);
#pragma unroll
    for (int e = 0; e < 8; ++e) {
      float2 cs = tab[s * 64 + dh0 + e];
      float x = bf2f(xs[e]);
      float r = lowh ? -bf2f(xp[e]) : bf2f(xp[e]);
      float o = x * cs.x + r * cs.y;
      if (isQ) o *= QSCALE;
      ov[e] = f2bf(o);
    }
    u16* dst;
    if (isQ) {
      int h = c >> 7;
      dst = Qb + ((size_t)h * S_LEN + s) * HD + d;
    } else {
      int kvh = (c - DMODEL) >> 7;
      dst = Kb + ((size_t)kvh * S_LEN + s) * HD + d;
    }
    *reinterpret_cast<ushort4*>(dst) = make_ushort4(ov[0], ov[1], ov[2], ov[3]);
    *reinterpret_cast<ushort4*>(dst + 4) = make_ushort4(ov[4], ov[5], ov[6], ov[7]);
  }
}

// ---------------- m97-style 128x128 GEMM, B^T operand ----------------
// (No XCD swizzle: operands are L3-resident; R14 A/B showed swizzle costs ~5us.)
template <int OUT_BF16>
__global__ __launch_bounds__(256) void k_gemm_bt(const u16* __restrict__ A,
                                                 const u16* __restrict__ BT,
                                                 void* __restrict__ C, int M, int N, int K) {
  __shared__ __align__(16) u16 As[128 * 32];
  __shared__ __align__(16) u16 Bs[128 * 32];
  const int tid = threadIdx.x, wave = tid >> 6, lane = tid & 63;
  const int fr = lane & 15, fq = lane >> 4;
  const int rowBase = blockIdx.y * 128, colBase = blockIdx.x * 128;
  const int wr = wave >> 1, wc = wave & 1;
  f32x4 acc[4][4] = {};
  const int nk = K >> 5;
  for (int kt = 0; kt < nk; ++kt) {
    const int k0 = kt << 5;
#pragma unroll
    for (int p = 0; p < 2; ++p) {
      int cbase = p * 256 + wave * 64;
      int chunk = cbase + lane;
      int r = chunk >> 2, cb = chunk & 3;
      gload16(A + (size_t)(rowBase + r) * K + k0 + cb * 8, (char*)As + cbase * 16);
      gload16(BT + (size_t)(colBase + r) * K + k0 + cb * 8, (char*)Bs + cbase * 16);
    }
    __syncthreads();
    bf16x8 a[4], b[4];
#pragma unroll
    for (int m = 0; m < 4; ++m)
      a[m] = *reinterpret_cast<const bf16x8*>(&As[(wr * 64 + m * 16 + fr) * 32 + fq * 8]);
#pragma unroll
    for (int n = 0; n < 4; ++n)
      b[n] = *reinterpret_cast<const bf16x8*>(&Bs[(wc * 64 + n * 16 + fr) * 32 + fq * 8]);
#pragma unroll
    for (int m = 0; m < 4; ++m)
#pragma unroll
      for (int n = 0; n < 4; ++n)
        acc[m][n] = __builtin_amdgcn_mfma_f32_16x16x32_bf16(a[m], b[n], acc[m][n], 0, 0, 0);
    __syncthreads();
  }
#pragma unroll
  for (int m = 0; m < 4; ++m) {
    int row0 = rowBase + wr * 64 + m * 16 + fq * 4;
#pragma unroll
    for (int n = 0; n < 4; ++n) {
      int col = colBase + wc * 64 + n * 16 + fr;
#pragma unroll
      for (int j = 0; j < 4; ++j) {
        if (OUT_BF16)
          ((u16*)C)[(size_t)(row0 + j) * N + col] = f2bf(acc[m][n][j]);
        else
          ((float*)C)[(size_t)(row0 + j) * N + col] = acc[m][n][j];
      }
    }
  }
}

// ---------------- flash attention (causal, GQA) ----------------
// 16x16 low-register design: 8 waves x 16 q-rows, KT=64, each wave covers ALL
// 64 k-cols (no k-group split, no in-block combine). Per-wave state ~110 regs
// (o 32 + st 16 + qf 16) <= 128 AND LDS 64KB -> 2 blocks/CU = 16 waves/CU
// (R12 proved co-residency happens when both constraints clear).
// Even/odd-kt e-split (R13-proven): grid (NH,16,2), every block exactly 33
// steps; raw bf16 partials Op + (m,l) -> k_comb merges.
// Fragment layouts = the GEMM-verified 16x16x32 mappings:
//   A[row=l&15][k=(l>>4)*8+e], B[k=(l>>4)*8+e][col=l&15], C/D row=(l>>4)*4+j.
// QK: S^T[k][q] = mfma(A=K-tile rows, B=Q) -> lane(fr=q, fq) holds
//   k = T*16 + fq*4 + j. PV: O^T[d][q] = mfma(A=V^T rows, B=P^T).
// P redistribution (k scattered over fq): target word w of kstep c comes from
// lane (fr, (fq&1)*2+(w>>1)), value = word(w&1) of tile T=2c+(fq>>1) -> 8
// shfl + 4 selects per kstep (corner-verified at 4 (fr,fq,c,w) points).
// Rule #20: all o[]/st[] indices compile-time static.
#define OP_ESTRIDE ((size_t)NH * 32 * 128 * 128)

__device__ __forceinline__ void stage_kv64(const u16* __restrict__ Kbk,
                                           const u16* __restrict__ VTk, int kb,
                                           char* KsB, char* VsB, int tid) {
#pragma unroll
  for (int it = 0; it < 2; ++it) {
    int slot = it * 512 + tid;              // 0..1023
    int r = slot >> 4, cb = slot & 15;      // K: 64 rows x 16 cells of 16B
    gload16(Kbk + (size_t)(kb + r) * HD + (size_t)((cb ^ (r & 15)) * 8), KsB + slot * 16);
    int d = slot >> 3, vb = slot & 7;       // V: 128 rows x 8 cells of 16B
    gload16(VTk + (size_t)d * S_LEN + kb + (vb ^ (d & 7)) * 8, VsB + slot * 16);
  }
}

__global__ __launch_bounds__(512, 2) void k_attn(const u16* __restrict__ Qb,
                                                 const u16* __restrict__ Kb,
                                                 const u16* __restrict__ VT,
                                                 u16* __restrict__ Op,
                                                 float2* __restrict__ mlG) {
  __shared__ __align__(16) u16 Ks[2][64 * 128];  // [k][d], cell ^(k&15), 32KB
  __shared__ __align__(16) u16 Vs[2][128 * 64];  // [d][k], cell ^(d&7),  32KB
  const int h = blockIdx.x;
  const int p = blockIdx.y;   // 0..15
  const int e = blockIdx.z;   // kt parity
  const int kv = h >> 2;
  const int tid = threadIdx.x, wave = tid >> 6, lane = tid & 63;
  const int fr = lane & 15, fq = lane >> 4;
  const float DEFER_THR = 11.541560327111707f;  // 8 * log2(e)

  const u16* Kbk = Kb + (size_t)kv * S_LEN * HD;
  const u16* VTk = VT + (size_t)kv * HD * S_LEN;

#pragma unroll 1
  for (int half = 0; half < 2; ++half) {
    const int qt = half ? p : (31 - p);
    const int qg0w = qt * 128 + wave * 16;  // wave's first q row
    const int qglob = qg0w + fr;            // this lane's q row

    stage_kv64(Kbk, VTk, e * 64, (char*)Ks[0], (char*)Vs[0], tid);

    // Q as B-operand frags: lane(fr,fq) holds Q[qglob][ds*32 + fq*8 + elem]
    bf16x8 qf[4];
    {
      const u16* qp = Qb + ((size_t)h * S_LEN + qglob) * HD;
#pragma unroll
      for (int ds = 0; ds < 4; ++ds)
        qf[ds] = *reinterpret_cast<const bf16x8*>(qp + ds * 32 + fq * 8);
    }
    f32x4 o[8] = {};  // O^T: o[dt][j] = O[q=fr][d = dt*16 + fq*4 + j]
    float m = -INFINITY, l = 0.f;

    __syncthreads();  // tile staged

    int buf = 0;
    const int nkt = 2 * qt + 2;
    for (int kt = e; kt < nkt; kt += 2) {
      if (kt + 2 < nkt)
        stage_kv64(Kbk, VTk, (kt + 2) * 64, (char*)Ks[buf ^ 1], (char*)Vs[buf ^ 1], tid);
      const int kb = kt * 64;
      if (kb <= qg0w + 15) {  // wave has >=1 unmasked column (kb<=qg0w always)
        const char* Kc = (const char*)Ks[buf];
        const char* Vc = (const char*)Vs[buf];

        // S^T = mfma(A=K rows, B=Q): st[T][j] = S^T[k=T*16+fq*4+j][q=fr]
        f32x4 st[4] = {};
#pragma unroll
        for (int ds = 0; ds < 4; ++ds) {
#pragma unroll
          for (int T = 0; T < 4; ++T) {
            bf16x8 kf = *reinterpret_cast<const bf16x8*>(
                Kc + (T * 16 + fr) * 256 + (((ds * 4 + fq) ^ fr) * 16));
            st[T] = __builtin_amdgcn_mfma_f32_16x16x32_bf16(kf, qf[ds], st[T], 0, 0, 0);
          }
        }
        // causal mask
        if (kb + 63 > qg0w) {
#pragma unroll
          for (int T = 0; T < 4; ++T)
#pragma unroll
            for (int j = 0; j < 4; ++j)
              if (kb + T * 16 + fq * 4 + j > qglob) st[T][j] = -1e30f;
        }
        // row max: 15-op in-lane tree + 2 shfl (lanes fr, fr+16, fr+32, fr+48)
        float mx;
        {
          float t0 = fmaxf(fmaxf(st[0][0], st[0][1]), fmaxf(st[0][2], st[0][3]));
          float t1 = fmaxf(fmaxf(st[1][0], st[1][1]), fmaxf(st[1][2], st[1][3]));
          float t2 = fmaxf(fmaxf(st[2][0], st[2][1]), fmaxf(st[2][2], st[2][3]));
          float t3 = fmaxf(fmaxf(st[3][0], st[3][1]), fmaxf(st[3][2], st[3][3]));
          mx = fmaxf(fmaxf(t0, t1), fmaxf(t2, t3));
          mx = fmaxf(mx, __shfl_xor(mx, 16));
          mx = fmaxf(mx, __shfl_xor(mx, 32));
        }
        // defer-max (T13)
        if (__any(mx - m > DEFER_THR)) {
          float mn = fmaxf(m, mx);
          float corr = exp2f(m - mn);
          m = mn;
          l *= corr;
#pragma unroll
          for (int dt = 0; dt < 8; ++dt) o[dt] *= corr;
        }
        // P = exp2(S - m); sum
        float s = 0.f;
#pragma unroll
        for (int T = 0; T < 4; ++T)
#pragma unroll
          for (int j = 0; j < 4; ++j) {
            float pv = exp2f(st[T][j] - m);
            st[T][j] = pv;
            s += pv;
          }
        s += __shfl_xor(s, 16);
        s += __shfl_xor(s, 32);
        l += s;

        // pack P words per tile: wA=pk2(j0,j1), wB=pk2(j2,j3)
        u32 wA[4], wB[4];
#pragma unroll
        for (int T = 0; T < 4; ++T) {
          wA[T] = pk2(st[T][0], st[T][1]);
          wB[T] = pk2(st[T][2], st[T][3]);
        }
        const int b2 = (fq & 1) * 2;
        const int src0 = fr + 16 * b2, src1 = src0 + 16;
        const bool hiT = (fq >= 2);
        // PV per kstep c (32 k): build P^T B-frag via 8 shfl + 4 selects
#pragma unroll
        for (int c = 0; c < 2; ++c) {
          u32 aLo0 = (u32)__shfl((int)wA[2 * c], src0);
          u32 aHi0 = (u32)__shfl((int)wA[2 * c + 1], src0);
          u32 bLo0 = (u32)__shfl((int)wB[2 * c], src0);
          u32 bHi0 = (u32)__shfl((int)wB[2 * c + 1], src0);
          u32 aLo1 = (u32)__shfl((int)wA[2 * c], src1);
          u32 aHi1 = (u32)__shfl((int)wA[2 * c + 1], src1);
          u32 bLo1 = (u32)__shfl((int)wB[2 * c], src1);
          u32 bHi1 = (u32)__shfl((int)wB[2 * c + 1], src1);
          i32x4 pw;
          pw[0] = (int)(hiT ? aHi0 : aLo0);
          pw[1] = (int)(hiT ? bHi0 : bLo0);
          pw[2] = (int)(hiT ? aHi1 : aLo1);
          pw[3] = (int)(hiT ? bHi1 : bLo1);
          bf16x8 pf = __builtin_bit_cast(bf16x8, pw);
#pragma unroll
          for (int dt = 0; dt < 8; ++dt) {
            bf16x8 vf = *reinterpret_cast<const bf16x8*>(
                Vc + (dt * 16 + fr) * 128 + (((c * 4 + fq) ^ (fr & 7)) * 16));
            o[dt] = __builtin_amdgcn_mfma_f32_16x16x32_bf16(vf, pf, o[dt], 0, 0, 0);
          }
        }
      }
      __syncthreads();  // next tile staged; buf safe to flip
      buf ^= 1;
    }

    // epilogue: raw bf16 partials (k_comb normalizes); no LDS use
    {
      u16* opRow = Op + (size_t)e * OP_ESTRIDE +
                   (((size_t)h * 32 + qt) * 128 + wave * 16 + fr) * 128;
#pragma unroll
      for (int dt = 0; dt < 8; ++dt) {
        int d0 = dt * 16 + fq * 4;
        *reinterpret_cast<u32*>(opRow + d0) = pk2(o[dt][0], o[dt][1]);
        *reinterpret_cast<u32*>(opRow + d0 + 2) = pk2(o[dt][2], o[dt][3]);
      }
      if (fq == 0)
        mlG[(((size_t)e * NH + h) * 32 + qt) * 128 + wave * 16 + fr] = make_float2(m, l);
    }
  }
}

// flash-combine of the 2 e-blocks (R13-proven):
// AO[s][h*HD+d] = (O0 w0 + O1 w1) / (l0 w0 + l1 w1)
__global__ void k_comb(const u16* __restrict__ Op, const float2* __restrict__ mlG,
                       u16* __restrict__ AO) {
  int s = blockIdx.x, h = blockIdx.y;
  int qt = s >> 7, row = s & 127;
  int t = threadIdx.x;  // 64 threads x 2 d
  size_t base = (((size_t)h * 32 + qt) * 128 + row) * 128;
  float2 ml0 = mlG[(((size_t)0 * NH + h) * 32 + qt) * 128 + row];
  float2 ml1 = mlG[(((size_t)1 * NH + h) * 32 + qt) * 128 + row];
  float M = fmaxf(ml0.x, ml1.x);
  float w0 = (ml0.x > -INFINITY) ? exp2f(ml0.x - M) : 0.f;
  float w1 = (ml1.x > -INFINITY) ? exp2f(ml1.x - M) : 0.f;
  float inv = 1.0f / (ml0.y * w0 + ml1.y * w1);
  u32 a = *reinterpret_cast<const u32*>(Op + base + t * 2);
  u32 b = *reinterpret_cast<const u32*>(Op + OP_ESTRIDE + base + t * 2);
  float o0 = bf2f((u16)a) * w0 + bf2f((u16)b) * w1;
  float o1 = bf2f((u16)(a >> 16)) * w0 + bf2f((u16)(b >> 16)) * w1;
  *reinterpret_cast<u32*>(AO + (size_t)s * DMODEL + h * HD + t * 2) = pk2(o0 * inv, o1 * inv);
}

// ---------------- launch ----------------
extern "C" void kernel_launch(void* const* d_in, const int* in_sizes, int n_in,
                              void* d_out, int out_size, void* d_ws, size_t ws_size,
                              hipStream_t stream) {
  const float* hidden = (const float*)d_in[0];
  const float* Wq = (const float*)d_in[1];
  const float* Wk = (const float*)d_in[2];
  const float* Wv = (const float*)d_in[3];
  const float* Wo = (const float*)d_in[4];
  // d_in[5] = attention_mask: causal, applied analytically (unused)
  const int* pos_ids = (const int*)d_in[6];
  float* out = (float*)d_out;

  // R13-proven workspace layout (<= 81MB). Lifetimes:
  //  WoT   0..8    transposes -> gemm2
  //  Wt    8..20   transposes -> gemm1 (dead after)
  //  Qb    8..24   rope -> attn (after Wt dead)
  //  Kb   24..28   rope -> attn
  //  VT   28..32   transposeV -> attn
  //  Xb   32..48   pack -> gemm1;  AO 32..48  comb -> gemm2 (after Xb dead)
  //  tab  48..50   rope_tab -> rope
  //  QKVb 50..74   gemm1 -> rope/transposeV
  //  Op   48..80   attn -> comb (after tab/QKVb dead)
  //  ml   80..81   attn -> comb
  char* ws = (char*)d_ws;
  u16* WoT  = (u16*)(ws);
  u16* Wt   = (u16*)(ws + (8ull << 20));
  u16* Qb   = (u16*)(ws + (8ull << 20));   // after Wt dead
  u16* Kb   = (u16*)(ws + (24ull << 20));
  u16* VT   = (u16*)(ws + (28ull << 20));
  u16* Xb   = (u16*)(ws + (32ull << 20));
  u16* AO   = (u16*)(ws + (32ull << 20));  // after Xb dead
  float2* tab = (float2*)(ws + (48ull << 20));
  u16* QKVb = (u16*)(ws + (50ull << 20));
  u16* Op   = (u16*)(ws + (48ull << 20));  // after tab/QKVb dead
  float2* mlG = (float2*)(ws + (80ull << 20));

  dim3 tb(32, 8);
  k_f32_to_bf16<<<dim3((S_LEN * DMODEL / 4) / 256), dim3(256), 0, stream>>>(
      hidden, Xb, S_LEN * DMODEL / 4);
  k_transpose_f32_bf16<<<dim3(64, 64), tb, 0, stream>>>(Wq, 2048, Wt, 2048);
  k_transpose_f32_bf16<<<dim3(16, 64), tb, 0, stream>>>(Wk, 512, Wt + (size_t)2048 * 2048, 2048);
  k_transpose_f32_bf16<<<dim3(16, 64), tb, 0, stream>>>(Wv, 512, Wt + (size_t)2560 * 2048, 2048);
  k_transpose_f32_bf16<<<dim3(64, 64), tb, 0, stream>>>(Wo, 2048, WoT, 2048);
  k_rope_tab<<<dim3(S_LEN * 64 / 256), dim3(256), 0, stream>>>(pos_ids, tab);

  k_gemm_bt<1><<<dim3(24, 32), 256, 0, stream>>>(Xb, Wt, QKVb, S_LEN, NQKV, DMODEL);

  k_rope<<<dim3(S_LEN), 256, 0, stream>>>(QKVb, tab, Qb, Kb);
  k_transpose_bf16<<<dim3(16, 128), tb, 0, stream>>>(QKVb + 2560, NQKV, VT, S_LEN);

  k_attn<<<dim3(NH, 16, 2), 512, 0, stream>>>(Qb, Kb, VT, Op, mlG);
  k_comb<<<dim3(S_LEN, NH), 64, 0, stream>>>(Op, mlG, AO);

  k_gemm_bt<0><<<dim3(16, 32), 256, 0, stream>>>(AO, WoT, out, S_LEN, DMODEL, DMODEL);
}

// Round 16
// 278.647 us; speedup vs baseline: 1.2546x; 1.2546x over previous
//
#include <hip/hip_runtime.h>
#include <hip/hip_bf16.h>
#include <cstdint>
#include <cmath>

#define S_LEN 4096
#define DMODEL 2048
#define NH 16
#define NKV 4
#define HD 128
#define NQKV 3072  // 2048 Q + 512 K + 512 V

typedef unsigned short u16;
typedef unsigned int u32;
typedef __attribute__((ext_vector_type(8))) __bf16 bf16x8;
typedef __attribute__((ext_vector_type(4))) float f32x4;
typedef __attribute__((ext_vector_type(16))) float f32x16;
typedef __attribute__((ext_vector_type(4))) int i32x4;

__device__ __forceinline__ u16 f2bf(float f) {
  __bf16 h = (__bf16)f;  // RNE
  return __builtin_bit_cast(u16, h);
}
__device__ __forceinline__ float bf2f(u16 u) {
  return (float)__builtin_bit_cast(__bf16, u);
}
__device__ __forceinline__ u32 pk2(float a, float b) {
  return (u32)f2bf(a) | ((u32)f2bf(b) << 16);
}

__device__ __forceinline__ void gload16(const void* g, void* l) {
  __builtin_amdgcn_global_load_lds(
      (const __attribute__((address_space(1))) void*)g,
      (__attribute__((address_space(3))) void*)l, 16, 0, 0);
}

// ---------------- pack / convert ----------------
__global__ void k_f32_to_bf16(const float* __restrict__ src, u16* __restrict__ dst, int n4) {
  int i = blockIdx.x * blockDim.x + threadIdx.x;
  if (i < n4) {
    float4 v = reinterpret_cast<const float4*>(src)[i];
    ushort4 o = make_ushort4(f2bf(v.x), f2bf(v.y), f2bf(v.z), f2bf(v.w));
    reinterpret_cast<ushort4*>(dst)[i] = o;
  }
}

// dst[n][k] = bf16(src[k][n])
__global__ void k_transpose_f32_bf16(const float* __restrict__ src, int srcStride,
                                     u16* __restrict__ dst, int dstStride) {
  __shared__ float tile[32][33];
  int n0 = blockIdx.x * 32, k0 = blockIdx.y * 32;
  int tx = threadIdx.x, ty = threadIdx.y;  // 32 x 8
#pragma unroll
  for (int r = 0; r < 32; r += 8)
    tile[ty + r][tx] = src[(size_t)(k0 + ty + r) * srcStride + n0 + tx];
  __syncthreads();
#pragma unroll
  for (int r = 0; r < 32; r += 8)
    dst[(size_t)(n0 + ty + r) * dstStride + k0 + tx] = f2bf(tile[tx][ty + r]);
}

__global__ void k_transpose_bf16(const u16* __restrict__ src, int srcStride,
                                 u16* __restrict__ dst, int dstStride) {
  __shared__ u16 tile[32][33];
  int n0 = blockIdx.x * 32, k0 = blockIdx.y * 32;
  int tx = threadIdx.x, ty = threadIdx.y;  // 32 x 8
#pragma unroll
  for (int r = 0; r < 32; r += 8)
    tile[ty + r][tx] = src[(size_t)(k0 + ty + r) * srcStride + n0 + tx];
  __syncthreads();
#pragma unroll
  for (int r = 0; r < 32; r += 8)
    dst[(size_t)(n0 + ty + r) * dstStride + k0 + tx] = tile[tx][ty + r];
}

// ---------------- RoPE ----------------
__global__ void k_rope_tab(const int* __restrict__ pos_ids, float2* __restrict__ tab) {
  int idx = blockIdx.x * blockDim.x + threadIdx.x;  // 4096*64
  int s = idx >> 6, dh = idx & 63;
  const float L2B = 13.287712379549449f;  // log2(10000)
  float pos = (float)pos_ids[s];
  float invf = exp2f(-(float)dh * (L2B / 64.0f));
  float ang = pos * invf;
  tab[idx] = make_float2(cosf(ang), sinf(ang));
}

// Q gets 1/sqrt(HD) * LOG2E folded in (softmax runs in exp2 domain).
// Vectorized (G13): each thread handles 8 consecutive bf16.
__global__ void k_rope(const u16* __restrict__ qkv, const float2* __restrict__ tab,
                       u16* __restrict__ Qb, u16* __restrict__ Kb) {
  int s = blockIdx.x;
  const u16* row = qkv + (size_t)s * NQKV;
  const float QSCALE = 0.08838834764831845f * 1.4426950408889634f;
  const int NV = (DMODEL + NKV * HD) / 8;  // 320 vec-chunks of 8
  for (int v8 = threadIdx.x; v8 < NV; v8 += blockDim.x) {
    int c = v8 * 8;
    int d = c & 127;
    int dh0 = d & 63;
    bool lowh = (d < 64);
    ushort4 a0 = *reinterpret_cast<const ushort4*>(row + c);
    ushort4 a1 = *reinterpret_cast<const ushort4*>(row + c + 4);
    ushort4 b0 = *reinterpret_cast<const ushort4*>(row + (c ^ 64));
    ushort4 b1 = *reinterpret_cast<const ushort4*>(row + (c ^ 64) + 4);
    u16 xs[8] = {a0.x, a0.y, a0.z, a0.w, a1.x, a1.y, a1.z, a1.w};
    u16 xp[8] = {b0.x, b0.y, b0.z, b0.w, b1.x, b1.y, b1.z, b1.w};
    u16 ov[8];
    bool isQ = (c < DMODEL);
#pragma unroll
    for (int e = 0; e < 8; ++e) {
      float2 cs = tab[s * 64 + dh0 + e];
      float x = bf2f(xs[e]);
      float r = lowh ? -bf2f(xp[e]) : bf2f(xp[e]);
      float o = x * cs.x + r * cs.y;
      if (isQ) o *= QSCALE;
      ov[e] = f2bf(o);
    }
    u16* dst;
    if (isQ) {
      int h = c >> 7;
      dst = Qb + ((size_t)h * S_LEN + s) * HD + d;
    } else {
      int kvh = (c - DMODEL) >> 7;
      dst = Kb + ((size_t)kvh * S_LEN + s) * HD + d;
    }
    *reinterpret_cast<ushort4*>(dst) = make_ushort4(ov[0], ov[1], ov[2], ov[3]);
    *reinterpret_cast<ushort4*>(dst + 4) = make_ushort4(ov[4], ov[5], ov[6], ov[7]);
  }
}

// ---------------- m97-style 128x128 GEMM, B^T operand ----------------
// No XCD swizzle (R14 A/B: costs ~5us when operands are L3-resident).
template <int OUT_BF16>
__global__ __launch_bounds__(256) void k_gemm_bt(const u16* __restrict__ A,
                                                 const u16* __restrict__ BT,
                                                 void* __restrict__ C, int M, int N, int K) {
  __shared__ __align__(16) u16 As[128 * 32];
  __shared__ __align__(16) u16 Bs[128 * 32];
  const int tid = threadIdx.x, wave = tid >> 6, lane = tid & 63;
  const int fr = lane & 15, fq = lane >> 4;
  const int rowBase = blockIdx.y * 128, colBase = blockIdx.x * 128;
  const int wr = wave >> 1, wc = wave & 1;
  f32x4 acc[4][4] = {};
  const int nk = K >> 5;
  for (int kt = 0; kt < nk; ++kt) {
    const int k0 = kt << 5;
#pragma unroll
    for (int p = 0; p < 2; ++p) {
      int cbase = p * 256 + wave * 64;
      int chunk = cbase + lane;
      int r = chunk >> 2, cb = chunk & 3;
      gload16(A + (size_t)(rowBase + r) * K + k0 + cb * 8, (char*)As + cbase * 16);
      gload16(BT + (size_t)(colBase + r) * K + k0 + cb * 8, (char*)Bs + cbase * 16);
    }
    __syncthreads();
    bf16x8 a[4], b[4];
#pragma unroll
    for (int m = 0; m < 4; ++m)
      a[m] = *reinterpret_cast<const bf16x8*>(&As[(wr * 64 + m * 16 + fr) * 32 + fq * 8]);
#pragma unroll
    for (int n = 0; n < 4; ++n)
      b[n] = *reinterpret_cast<const bf16x8*>(&Bs[(wc * 64 + n * 16 + fr) * 32 + fq * 8]);
#pragma unroll
    for (int m = 0; m < 4; ++m)
#pragma unroll
      for (int n = 0; n < 4; ++n)
        acc[m][n] = __builtin_amdgcn_mfma_f32_16x16x32_bf16(a[m], b[n], acc[m][n], 0, 0, 0);
    __syncthreads();
  }
#pragma unroll
  for (int m = 0; m < 4; ++m) {
    int row0 = rowBase + wr * 64 + m * 16 + fq * 4;
#pragma unroll
    for (int n = 0; n < 4; ++n) {
      int col = colBase + wc * 64 + n * 16 + fr;
#pragma unroll
      for (int j = 0; j < 4; ++j) {
        if (OUT_BF16)
          ((u16*)C)[(size_t)(row0 + j) * N + col] = f2bf(acc[m][n][j]);
        else
          ((float*)C)[(size_t)(row0 + j) * N + col] = acc[m][n][j];
      }
    }
  }
}

// ---------------- flash attention (causal, GQA) ----------------
// R8/R11-proven kernel (139us, session best). 8 waves, 512 thr. Group A
// (waves 0-3) = k-cols 0..63 of each KT=128 step, group B (4-7) = 64..127;
// both cover the same 128 q-rows (4 pairs x 32q, swapped 32x32 MFMA +
// in-register softmax per wave). ONE flash-combine per q-tile through LDS.
// Serial q-tile pair {31-p, p}: every block exactly 33 steps -> 256 blocks =
// 1/CU. Rule #20: all o[] indices static per-grp branch.
// Plateau note (R9-R15): 2-blocks/CU co-residency requires launch_bounds
// min-blocks>=4 (R12) which caps VGPR at 64 and spills this state; at
// (512,2) the runtime keeps 1 block/CU regardless of VGPR/LDS headroom.
// 139us = latency-bound at 2 waves/SIMD, ~494 TF (21% MFMA util).
// Qb [H][S][HD] (pre-scaled by 1/sqrt(HD)*LOG2E), Kb [KV][S][HD],
// VT [KV][HD][S], AO [S][H*HD]
__device__ __forceinline__ void stage_kv128(const u16* __restrict__ Kbk,
                                            const u16* __restrict__ VTk, int kb,
                                            char* KsB, char* VsB, int tid) {
#pragma unroll
  for (int it = 0; it < 4; ++it) {
    int slot = it * 512 + tid;
    int r = slot >> 4, cb = slot & 15;
    int cbs = cb ^ (r & 15);  // pre-swizzled source -> linear LDS dest (G21)
    gload16(Kbk + (size_t)(kb + r) * HD + cbs * 8, KsB + slot * 16);
    gload16(VTk + (size_t)r * S_LEN + kb + cbs * 8, VsB + slot * 16);
  }
}

__global__ __launch_bounds__(512, 2) void k_attn(const u16* __restrict__ Qb,
                                                 const u16* __restrict__ Kb,
                                                 const u16* __restrict__ VT,
                                                 u16* __restrict__ AO) {
  __shared__ __align__(16) u16 Ks[2][128 * 128];  // [k][d], ^(k&15) chunk swz, 64KB
  __shared__ __align__(16) u16 Vs[2][128 * 128];  // [d][k], ^(d&15) chunk swz, 64KB
  const int h = blockIdx.x;
  const int p = blockIdx.y;  // 0..15
  const int kv = h >> 2;
  const int tid = threadIdx.x, wave = tid >> 6, lane = tid & 63;
  const int grp = wave >> 2, pr = wave & 3;  // k-group, q-pair
  const int ql = lane & 31, hi = lane >> 5;
  const float DEFER_THR = 11.541560327111707f;  // 8 * log2(e)

  const u16* Kbk = Kb + (size_t)kv * S_LEN * HD;
  const u16* VTk = VT + (size_t)kv * HD * S_LEN;

#pragma unroll 1
  for (int half = 0; half < 2; ++half) {
    const int qt = half ? p : (31 - p);
    const int qg0w = qt * 128 + pr * 32;  // wave's first q row
    const int qglob = qg0w + ql;          // this lane's q row

    __syncthreads();  // prior combine LDS readers done before restaging
    stage_kv128(Kbk, VTk, 0, (char*)Ks[0], (char*)Vs[0], tid);

    // Q as B-operand frags: lane(ql,hi) holds Q[qglob][t*16 + hi*8 + e]
    bf16x8 qf[8];
    {
      const u16* qp = Qb + ((size_t)h * S_LEN + qglob) * HD;
#pragma unroll
      for (int t = 0; t < 8; ++t)
        qf[t] = *reinterpret_cast<const bf16x8*>(qp + t * 16 + hi * 8);
    }
    f32x16 o[4] = {};  // O^T: lane(q=ql,hi) holds O[q][d0*32+(r&3)+8*(r>>2)+4*hi]
    float m = -INFINITY, l = 0.f;

    __syncthreads();  // tile 0 staged

    int buf = 0;
    const int nkt = qt + 1;
    for (int kt = 0; kt < nkt; ++kt) {
      if (kt + 1 < nkt)
        stage_kv128(Kbk, VTk, (kt + 1) * 128, (char*)Ks[buf ^ 1], (char*)Vs[buf ^ 1], tid);
      const int kbg = kt * 128 + grp * 64;  // this group's k base
      if (kbg <= qg0w + 31) {               // wave has >=1 unmasked column
        const char* Kc = (const char*)Ks[buf];
        const char* Vc = (const char*)Vs[buf];

        // S^T = mfma(A=K rows, B=Q): st0 = group k 0..31, st1 = 32..63
        f32x16 st0 = {}, st1 = {};
#pragma unroll
        for (int t = 0; t < 8; ++t) {
          int ch = (2 * t + hi) ^ (ql & 15);
          const int r0 = grp * 64 + ql, r1 = grp * 64 + 32 + ql;
          bf16x8 kf0 = *reinterpret_cast<const bf16x8*>(Kc + r0 * 256 + ch * 16);
          bf16x8 kf1 = *reinterpret_cast<const bf16x8*>(Kc + r1 * 256 + ch * 16);
          st0 = __builtin_amdgcn_mfma_f32_32x32x16_bf16(kf0, qf[t], st0, 0, 0, 0);
          st1 = __builtin_amdgcn_mfma_f32_32x32x16_bf16(kf1, qf[t], st1, 0, 0, 0);
        }
        // causal mask: lane reg r holds k_local = (r&3)+8*(r>>2)+4*hi
        if (kbg + 63 > qg0w) {
#pragma unroll
          for (int r = 0; r < 16; ++r) {
            int kl = (r & 3) + 8 * (r >> 2) + 4 * hi;
            if (kbg + kl > qglob) st0[r] = -1e30f;
            if (kbg + 32 + kl > qglob) st1[r] = -1e30f;
          }
        }
        // row max: in-lane tree over 32 values, then lane-pair combine (xor 32)
        float mx[16];
#pragma unroll
        for (int r = 0; r < 16; ++r) mx[r] = fmaxf(st0[r], st1[r]);
#pragma unroll
        for (int s = 8; s > 0; s >>= 1)
#pragma unroll
          for (int r = 0; r < 16; ++r)
            if (r < s) mx[r] = fmaxf(mx[r], mx[r + s]);
        float tmax = fmaxf(mx[0], __shfl_xor(mx[0], 32));
        // defer-max (T13)
        if (__any(tmax - m > DEFER_THR)) {
          float mn = fmaxf(m, tmax);
          float corr = exp2f(m - mn);
          m = mn;
          l *= corr;
#pragma unroll
          for (int d0 = 0; d0 < 4; ++d0) o[d0] *= corr;
        }
        // P = exp2(S - m); in-lane sum + lane-pair combine
        float sm[16];
#pragma unroll
        for (int r = 0; r < 16; ++r) {
          st0[r] = exp2f(st0[r] - m);
          st1[r] = exp2f(st1[r] - m);
          sm[r] = st0[r] + st1[r];
        }
#pragma unroll
        for (int s = 8; s > 0; s >>= 1)
#pragma unroll
          for (int r = 0; r < 16; ++r)
            if (r < s) sm[r] += sm[r + s];
        l += sm[0] + __shfl_xor(sm[0], 32);

        // P -> bf16 B-frags in-register (pack + shfl_xor(32) + select).
        // Frag slot (hi,e) holds P[q][kc*16 + hi*8 + e] (k local to group).
        bf16x8 pa[4];
#pragma unroll
        for (int kc = 0; kc < 4; ++kc) {
          int rb = 8 * (kc & 1);
          u32 w0, w1, w2, w3;
          if (kc < 2) {
            w0 = pk2(st0[rb + 0], st0[rb + 1]);
            w1 = pk2(st0[rb + 2], st0[rb + 3]);
            w2 = pk2(st0[rb + 4], st0[rb + 5]);
            w3 = pk2(st0[rb + 6], st0[rb + 7]);
          } else {
            w0 = pk2(st1[rb + 0], st1[rb + 1]);
            w1 = pk2(st1[rb + 2], st1[rb + 3]);
            w2 = pk2(st1[rb + 4], st1[rb + 5]);
            w3 = pk2(st1[rb + 6], st1[rb + 7]);
          }
          u32 xw0 = (u32)__shfl_xor((int)w0, 32);
          u32 xw1 = (u32)__shfl_xor((int)w1, 32);
          u32 xw2 = (u32)__shfl_xor((int)w2, 32);
          u32 xw3 = (u32)__shfl_xor((int)w3, 32);
          i32x4 pw;
          pw[0] = (int)(hi ? xw2 : w0);
          pw[1] = (int)(hi ? xw3 : w1);
          pw[2] = (int)(hi ? w2 : xw0);
          pw[3] = (int)(hi ? w3 : xw1);
          pa[kc] = __builtin_bit_cast(bf16x8, pw);
        }
        // O^T += mfma(A=V^T rows, B=P^T) over this group's 64 k-cols
#pragma unroll
        for (int d0 = 0; d0 < 4; ++d0) {
          int dr = d0 * 32 + ql;
#pragma unroll
          for (int kc = 0; kc < 4; ++kc) {
            int ch = (grp * 8 + 2 * kc + hi) ^ (ql & 15);
            bf16x8 vf = *reinterpret_cast<const bf16x8*>(Vc + dr * 256 + ch * 16);
            o[d0] = __builtin_amdgcn_mfma_f32_32x32x16_bf16(vf, pa[kc], o[d0], 0, 0, 0);
          }
        }
      }
      __syncthreads();  // next tile staged; buf safe to flip
      buf ^= 1;
    }

    // ---- flash-combine of the two k-groups (once per q-tile) ----
    // grp 0: stores o[2],o[3] for partner, merges+writes d0 0,1.
    // grp 1: stores o[0],o[1] for partner, merges+writes d0 2,3.
    // STATIC o[] indices only (rule #20) — branch on wave-uniform grp.
    float2* exch = (float2*)Ks;  // [d0 4][rp 8][pr 4][lane 64] float2 = 64KB
    float2* mlb = (float2*)Vs;   // [grp 2][pr 4][ql 32] float2
    if (grp == 0) {
#pragma unroll
      for (int rp = 0; rp < 8; ++rp) {
        float2 v2, v3;
        v2.x = o[2][2 * rp]; v2.y = o[2][2 * rp + 1];
        v3.x = o[3][2 * rp]; v3.y = o[3][2 * rp + 1];
        exch[((2 * 8 + rp) * 4 + pr) * 64 + lane] = v2;
        exch[((3 * 8 + rp) * 4 + pr) * 64 + lane] = v3;
      }
    } else {
#pragma unroll
      for (int rp = 0; rp < 8; ++rp) {
        float2 v0, v1;
        v0.x = o[0][2 * rp]; v0.y = o[0][2 * rp + 1];
        v1.x = o[1][2 * rp]; v1.y = o[1][2 * rp + 1];
        exch[((0 * 8 + rp) * 4 + pr) * 64 + lane] = v0;
        exch[((1 * 8 + rp) * 4 + pr) * 64 + lane] = v1;
      }
    }
    if (hi == 0) {
      float2 v;
      v.x = m;
      v.y = l;
      mlb[(grp * 4 + pr) * 32 + ql] = v;
    }
    __syncthreads();
    {
      float2 pml = mlb[((1 - grp) * 4 + pr) * 32 + ql];
      float mm = fmaxf(m, pml.x);
      float fa = exp2f(m - mm), fb = exp2f(pml.x - mm);
      float ll = l * fa + pml.y * fb;
      float inv = 1.0f / ll;
      u16* aoRow = AO + (size_t)qglob * DMODEL + h * HD;
      if (grp == 0) {
#pragma unroll
        for (int rp = 0; rp < 8; ++rp) {
          int r = 2 * rp;
          int dbase = (r & 3) + 8 * (r >> 2) + 4 * hi;
          float2 po0 = exch[((0 * 8 + rp) * 4 + pr) * 64 + lane];
          float u0 = (o[0][r] * fa + po0.x * fb) * inv;
          float u1 = (o[0][r + 1] * fa + po0.y * fb) * inv;
          *reinterpret_cast<u32*>(aoRow + 0 * 32 + dbase) = pk2(u0, u1);
          float2 po1 = exch[((1 * 8 + rp) * 4 + pr) * 64 + lane];
          u0 = (o[1][r] * fa + po1.x * fb) * inv;
          u1 = (o[1][r + 1] * fa + po1.y * fb) * inv;
          *reinterpret_cast<u32*>(aoRow + 1 * 32 + dbase) = pk2(u0, u1);
        }
      } else {
#pragma unroll
        for (int rp = 0; rp < 8; ++rp) {
          int r = 2 * rp;
          int dbase = (r & 3) + 8 * (r >> 2) + 4 * hi;
          float2 po2 = exch[((2 * 8 + rp) * 4 + pr) * 64 + lane];
          float u0 = (o[2][r] * fa + po2.x * fb) * inv;
          float u1 = (o[2][r + 1] * fa + po2.y * fb) * inv;
          *reinterpret_cast<u32*>(aoRow + 2 * 32 + dbase) = pk2(u0, u1);
          float2 po3 = exch[((3 * 8 + rp) * 4 + pr) * 64 + lane];
          u0 = (o[3][r] * fa + po3.x * fb) * inv;
          u1 = (o[3][r + 1] * fa + po3.y * fb) * inv;
          *reinterpret_cast<u32*>(aoRow + 3 * 32 + dbase) = pk2(u0, u1);
        }
      }
    }
    // loop-top __syncthreads protects Ks/Vs before next tile's staging
  }
}

// ---------------- launch ----------------
extern "C" void kernel_launch(void* const* d_in, const int* in_sizes, int n_in,
                              void* d_out, int out_size, void* d_ws, size_t ws_size,
                              hipStream_t stream) {
  const float* hidden = (const float*)d_in[0];
  const float* Wq = (const float*)d_in[1];
  const float* Wk = (const float*)d_in[2];
  const float* Wv = (const float*)d_in[3];
  const float* Wo = (const float*)d_in[4];
  // d_in[5] = attention_mask: causal, applied analytically (unused)
  const int* pos_ids = (const int*)d_in[6];
  float* out = (float*)d_out;

  char* ws = (char*)d_ws;
  u16* Xb   = (u16*)(ws);                               // [4096][2048]   16MB
  u16* Wt   = (u16*)(ws + (16ull << 20));               // [3072][2048]   12MB
  u16* WoT  = (u16*)(ws + (28ull << 20));               // [2048][2048]    8MB
  u16* QKVb = (u16*)(ws + (36ull << 20));               // [4096][3072]   24MB
  u16* Qb   = (u16*)(ws + (60ull << 20));               // [16][4096][128] 16MB
  u16* Kb   = (u16*)(ws + (76ull << 20));               // [4][4096][128]   4MB
  u16* VT   = (u16*)(ws + (80ull << 20));               // [4][128][4096]   4MB
  // tab overlaps VT's 2nd half (82..84MB). Lifetime per replay: rope_tab
  // writes tab -> gemm -> rope READS tab -> transpose writes VT (clobbers
  // dead tab) -> attn reads VT. Single stream => deterministic.
  float2* tab = (float2*)(ws + (82ull << 20));          // [4096][64]       2MB
  u16* AO   = QKVb;  // alias: QKVb fully consumed before attention writes AO

  dim3 tb(32, 8);
  k_f32_to_bf16<<<dim3((S_LEN * DMODEL / 4) / 256), dim3(256), 0, stream>>>(
      hidden, Xb, S_LEN * DMODEL / 4);
  k_transpose_f32_bf16<<<dim3(64, 64), tb, 0, stream>>>(Wq, 2048, Wt, 2048);
  k_transpose_f32_bf16<<<dim3(16, 64), tb, 0, stream>>>(Wk, 512, Wt + (size_t)2048 * 2048, 2048);
  k_transpose_f32_bf16<<<dim3(16, 64), tb, 0, stream>>>(Wv, 512, Wt + (size_t)2560 * 2048, 2048);
  k_transpose_f32_bf16<<<dim3(64, 64), tb, 0, stream>>>(Wo, 2048, WoT, 2048);
  k_rope_tab<<<dim3(S_LEN * 64 / 256), dim3(256), 0, stream>>>(pos_ids, tab);

  k_gemm_bt<1><<<dim3(24, 32), 256, 0, stream>>>(Xb, Wt, QKVb, S_LEN, NQKV, DMODEL);

  k_rope<<<dim3(S_LEN), 256, 0, stream>>>(QKVb, tab, Qb, Kb);
  k_transpose_bf16<<<dim3(16, 128), tb, 0, stream>>>(QKVb + 2560, NQKV, VT, S_LEN);

  k_attn<<<dim3(NH, 16), 512, 0, stream>>>(Qb, Kb, VT, AO);

  k_gemm_bt<0><<<dim3(16, 32), 256, 0, stream>>>(AO, WoT, out, S_LEN, DMODEL, DMODEL);
}